// Round 6
// baseline (2591.398 us; speedup 1.0000x reference)
//
#include <hip/hip_runtime.h>
#include <math.h>

// Problem constants
#define B_    256
#define NPTS  1024
#define T_    50

// ---------------------------------------------------------------------------
// ws layout (bytes):
//   [0,        786432)   wh4  f32 [64][768][4]  (W_hh packed: wh4[k4][o][c] = whh[o][4k4+c])
//   [786432,   1310720)  henc u32 [256][512]    (f32-bit maxpool via atomicMax)
//   [1310720,  1835008)  hg   f64 [128][256][2] (per-block GRU h mirror, [k][g])
// ---------------------------------------------------------------------------

__global__ __launch_bounds__(256) void prep_kernel(const float* __restrict__ whh,
                                                   float* __restrict__ wh4,
                                                   unsigned* __restrict__ henc) {
  int idx = blockIdx.x * 256 + threadIdx.x;   // grid 512*256 = 131072
  if (idx < 49152) {                          // idx = k4*768 + o
    int k4 = idx / 768, o = idx - k4 * 768;
    const float* __restrict__ src = whh + o * 256 + k4 * 4;
    float4 v = {src[0], src[1], src[2], src[3]};
    *(float4*)(wh4 + idx * 4) = v;            // coalesced 16B writes
  }
  if (idx < 131072) henc[idx] = 0u;           // bits 0 == +0.0f; relu>=0 valid
}

// ---------------------------------------------------------------------------
// Encoder, f32 (math order identical to passing rounds 3-5): block = half a
// sample (512 points), grid 512 -> 2 blocks/CU for latency hiding (round 5:
// grid 256 = 1/CU, VALU stalled on s_load latency). Wave w owns uniform
// output slice [32w,32w+32) -> all weight reads are scalar s_loads. Merge
// across the 2 blocks per sample via atomicMax on f32 bits (bit-monotone
// for nonneg floats; henc zeroed by prep).
// ---------------------------------------------------------------------------
__global__ __launch_bounds__(1024) void enc_kernel(
    const float* __restrict__ data,
    const float* __restrict__ w1, const float* __restrict__ b1,
    const float* __restrict__ w2, const float* __restrict__ b2,
    const float* __restrict__ w3, const float* __restrict__ b3,
    unsigned* __restrict__ henc) {
  __shared__ float h2t[128][66];
  const int t = threadIdx.x;
  const int b = blockIdx.x >> 1;
  const int half = blockIdx.x & 1;
  const int lane = t & 63;
  const int wv = __builtin_amdgcn_readfirstlane(t >> 6);   // wave id 0..15

  float m[32];
#pragma unroll
  for (int o = 0; o < 32; ++o) m[o] = 0.0f;                // relu via max w/ 0
  const float* __restrict__ w3b = w3 + wv * 32;

#pragma unroll 1
  for (int tile = 0; tile < 8; ++tile) {
    // ---- stage: this wave computes channels [8wv,8wv+8) of its lane's pt --
    {
      const int ptg = b * NPTS + half * 512 + tile * 64 + lane;
      const float x0 = data[ptg * 3], x1 = data[ptg * 3 + 1], x2 = data[ptg * 3 + 2];
      float a[8];
#pragma unroll
      for (int c = 0; c < 8; ++c) a[c] = b2[wv * 8 + c];   // s_load
#pragma unroll 4
      for (int j = 0; j < 64; ++j) {                       // w1/b1 uniform
        float hj = fmaf(x0, w1[j], fmaf(x1, w1[64 + j], fmaf(x2, w1[128 + j], b1[j])));
        hj = fmaxf(hj, 0.0f);
        const float* __restrict__ w2r = w2 + j * 128 + wv * 8;  // s_load x8
#pragma unroll
        for (int c = 0; c < 8; ++c) a[c] = fmaf(hj, w2r[c], a[c]);
      }
#pragma unroll
      for (int c = 0; c < 8; ++c) h2t[wv * 8 + c][lane] = fmaxf(a[c], 0.0f);
    }
    __syncthreads();

    // ---- GEMM: 64 pts (lanes) x 32 outs (this wave), k = 0..127 ----
    float acc[32];
#pragma unroll
    for (int o = 0; o < 32; ++o) acc[o] = b3[wv * 32 + o]; // s_load
#pragma unroll 2
    for (int k = 0; k < 128; ++k) {
      const float hk = h2t[k][lane];                       // ds_read_b32
      const float* __restrict__ wr = w3b + k * 512;        // uniform -> s_load
#pragma unroll
      for (int o = 0; o < 32; ++o) acc[o] = fmaf(hk, wr[o], acc[o]);
    }
#pragma unroll
    for (int o = 0; o < 32; ++o) m[o] = fmaxf(m[o], acc[o]);
    __syncthreads();                                       // h2t reuse guard
  }

  // ---- pool across the 64 point-lanes ----
#pragma unroll
  for (int off = 32; off > 0; off >>= 1) {
#pragma unroll
    for (int o = 0; o < 32; ++o) m[o] = fmaxf(m[o], __shfl_xor(m[o], off, 64));
  }
  if (lane == 0) {
    unsigned* __restrict__ hr = henc + b * 512 + wv * 32;
#pragma unroll
    for (int o = 0; o < 32; ++o) atomicMax(hr + o, __float_as_uint(m[o]));
  }
}

// ---------------------------------------------------------------------------
// GRU rollout, f64 internal. Block = 2 samples, 1024 threads, grid 128.
// h state: owner-register (gate thread) -> per-block GLOBAL mirror hg ->
// consumed by matvec/out_mlp at wave-uniform addresses = scalar s_loads
// (frees the LDS pipe that gated round 5: 3k ds_read/step/CU). Coherence:
// __syncthreads + s_dcache_inv after each h update. W_hh read from the wh4
// packed layout: per k4 one fully-coalesced 16B float4 per lane (round 5's
// per-lane row walk scattered 64 lines/instr). Waves 12-15 run out_mlp
// concurrently with the matvec chunks (round-4 structure).
// f64 reassociation is invisible at f32 output rounding (round-4 evidence).
// ---------------------------------------------------------------------------
__global__ __launch_bounds__(1024) void gru_kernel(
    const float* __restrict__ henc,     // [256][512] (maxpool bits)
    const float* __restrict__ mw1, const float* __restrict__ mb1,
    const float* __restrict__ mw2, const float* __restrict__ mb2,
    const float* __restrict__ mw3, const float* __restrict__ mb3,
    const float* __restrict__ wih, const float* __restrict__ wh4,
    const float* __restrict__ bih, const float* __restrict__ bhh,
    const float* __restrict__ ow1, const float* __restrict__ ob1,
    const float* __restrict__ ow2, const float* __restrict__ ob2,
    const float* __restrict__ ow3, const float* __restrict__ ob3,
    double* __restrict__ hg_all, float* __restrict__ dout) {
  __shared__ double comb_l[768 * 2];   // bhh + Whh@h, [o][g]
  __shared__ double g1_l[256 * 2];
  __shared__ double g2_l[128 * 2];
  __shared__ double o1_l[64 * 2];
  __shared__ double o2_l[64 * 2];
  __shared__ double gia_l[12];         // gi accumulator, [g][c]
  __shared__ float wih_l[768 * 6];
  __shared__ float bih_l[768];

  const int t = threadIdx.x;
  const int s0 = blockIdx.x << 1;
  const double* __restrict__ hgc = hg_all + (blockIdx.x << 9);  // [k][g] f64
  double* __restrict__ hgw = hg_all + (blockIdx.x << 9);

  for (int i = t; i < 768 * 6; i += 1024) wih_l[i] = wih[i];
  if (t < 768) bih_l[t] = bih[t];

  // ---- phase 0: gru_h init MLP (512->256->128->256), f64 ----
  if (t < 512) {
    const int o = t & 255, g = t >> 8;                    // g wave-uniform
    const float* __restrict__ hrow = henc + ((s0 + g) << 9);   // uniform
    double a = (double)mb1[o];
#pragma unroll 4
    for (int k = 0; k < 512; ++k)
      a = fma((double)hrow[k], (double)mw1[k * 256 + o], a);
    g1_l[o * 2 + g] = fmax(a, 0.0);
  }
  __syncthreads();
  if (t < 256) {
    const int o = t & 127, g = t >> 7;
    double a = (double)mb2[o];
#pragma unroll 4
    for (int k = 0; k < 256; ++k) a = fma(g1_l[k * 2 + g], (double)mw2[k * 128 + o], a);
    g2_l[o * 2 + g] = fmax(a, 0.0);
  }
  __syncthreads();
  double hreg = 0.0;                   // gate thread (i,g) owns h[i][g]
  if (t < 512) {
    const int o = t & 255, g = t >> 8;
    double a = (double)mb3[o];
#pragma unroll 4
    for (int k = 0; k < 128; ++k) a = fma(g2_l[k * 2 + g], (double)mw3[k * 256 + o], a);
    hreg = a;
    hgw[o * 2 + g] = a;
  }
  if (t < 12) gia_l[t] = 0.0;
  __syncthreads();
  asm volatile("s_dcache_inv" ::: "memory");

  // per-matvec-thread constants
  const double bhh_o = (t < 768) ? (double)bhh[t] : 0.0;
  const float* __restrict__ w4p = wh4 + (t < 768 ? t : 0) * 4;
  const int tb = t - 768;

  // ---- prologue: comb = bhh + Whh @ h0 ----
  if (t < 768) {
    double a0 = bhh_o, a1 = bhh_o;
#pragma unroll 2
    for (int k4 = 0; k4 < 64; ++k4) {
      const float4 w4 = *(const float4*)(w4p + k4 * 3072);     // coalesced 16B
      const double2 h0 = *(const double2*)(hgc + (k4 << 3));   // uniform s_load
      const double2 h1 = *(const double2*)(hgc + (k4 << 3) + 2);
      const double2 h2 = *(const double2*)(hgc + (k4 << 3) + 4);
      const double2 h3 = *(const double2*)(hgc + (k4 << 3) + 6);
      a0 = fma(h0.x, (double)w4.x, a0); a1 = fma(h0.y, (double)w4.x, a1);
      a0 = fma(h1.x, (double)w4.y, a0); a1 = fma(h1.y, (double)w4.y, a1);
      a0 = fma(h2.x, (double)w4.z, a0); a1 = fma(h2.y, (double)w4.z, a1);
      a0 = fma(h3.x, (double)w4.w, a0); a1 = fma(h3.y, (double)w4.w, a1);
    }
    comb_l[t * 2 + 0] = a0; comb_l[t * 2 + 1] = a1;
  }
  __syncthreads();

  for (int step = 0; step < T_; ++step) {
    // ---- G: gates + h update (t<512); gi 6-dot folded in ----
    if (t < 512) {
      const int i = t & 255, g = t >> 8;
      double gr = (double)bih_l[i], gz = (double)bih_l[256 + i],
             gn = (double)bih_l[512 + i];
#pragma unroll
      for (int a = 0; a < 6; ++a) {
        const double xa = gia_l[g * 6 + a];
        gr = fma((double)wih_l[i * 6 + a], xa, gr);
        gz = fma((double)wih_l[(256 + i) * 6 + a], xa, gz);
        gn = fma((double)wih_l[(512 + i) * 6 + a], xa, gn);
      }
      const double rv = 1.0 / (1.0 + exp(-(comb_l[i * 2 + g] + gr)));
      const double zv = 1.0 / (1.0 + exp(-(comb_l[(256 + i) * 2 + g] + gz)));
      const double nv = tanh(fma(rv, comb_l[(512 + i) * 2 + g], gn));
      hreg = fma(zv, hreg - nv, nv);
      hgw[i * 2 + g] = hreg;
    }
    __syncthreads();
    asm volatile("s_dcache_inv" ::: "memory");

    // ---- C1/C2/C3: matvec chunks (t<768) || out_mlp stages (t>=768) ----
    double a0 = bhh_o, a1 = bhh_o;
    if (t < 768) {
#pragma unroll 2
      for (int k4 = 0; k4 < 22; ++k4) {
        const float4 w4 = *(const float4*)(w4p + k4 * 3072);
        const double2 h0 = *(const double2*)(hgc + (k4 << 3));
        const double2 h1 = *(const double2*)(hgc + (k4 << 3) + 2);
        const double2 h2 = *(const double2*)(hgc + (k4 << 3) + 4);
        const double2 h3 = *(const double2*)(hgc + (k4 << 3) + 6);
        a0 = fma(h0.x, (double)w4.x, a0); a1 = fma(h0.y, (double)w4.x, a1);
        a0 = fma(h1.x, (double)w4.y, a0); a1 = fma(h1.y, (double)w4.y, a1);
        a0 = fma(h2.x, (double)w4.z, a0); a1 = fma(h2.y, (double)w4.z, a1);
        a0 = fma(h3.x, (double)w4.w, a0); a1 = fma(h3.y, (double)w4.w, a1);
      }
    } else if (tb < 128) {             // out_mlp layer 1 (h -> 64)
      const int j = tb & 63, g = tb >> 6;
      double a = (double)ob1[j];
#pragma unroll 4
      for (int k = 0; k < 256; ++k)
        a = fma(hgc[k * 2 + g], (double)ow1[k * 64 + j], a);   // h via s_load
      o1_l[j * 2 + g] = fmax(a, 0.0);
    }
    __syncthreads();

    if (t < 768) {
#pragma unroll 2
      for (int k4 = 22; k4 < 43; ++k4) {
        const float4 w4 = *(const float4*)(w4p + k4 * 3072);
        const double2 h0 = *(const double2*)(hgc + (k4 << 3));
        const double2 h1 = *(const double2*)(hgc + (k4 << 3) + 2);
        const double2 h2 = *(const double2*)(hgc + (k4 << 3) + 4);
        const double2 h3 = *(const double2*)(hgc + (k4 << 3) + 6);
        a0 = fma(h0.x, (double)w4.x, a0); a1 = fma(h0.y, (double)w4.x, a1);
        a0 = fma(h1.x, (double)w4.y, a0); a1 = fma(h1.y, (double)w4.y, a1);
        a0 = fma(h2.x, (double)w4.z, a0); a1 = fma(h2.y, (double)w4.z, a1);
        a0 = fma(h3.x, (double)w4.w, a0); a1 = fma(h3.y, (double)w4.w, a1);
      }
    } else if (tb < 128) {             // out_mlp layer 2 (64 -> 64)
      const int j = tb & 63, g = tb >> 6;
      double a = (double)ob2[j];
#pragma unroll 4
      for (int k = 0; k < 64; ++k) a = fma(o1_l[k * 2 + g], (double)ow2[k * 64 + j], a);
      o2_l[j * 2 + g] = fmax(a, 0.0);
    }
    __syncthreads();

    if (t < 768) {
#pragma unroll 2
      for (int k4 = 43; k4 < 64; ++k4) {
        const float4 w4 = *(const float4*)(w4p + k4 * 3072);
        const double2 h0 = *(const double2*)(hgc + (k4 << 3));
        const double2 h1 = *(const double2*)(hgc + (k4 << 3) + 2);
        const double2 h2 = *(const double2*)(hgc + (k4 << 3) + 4);
        const double2 h3 = *(const double2*)(hgc + (k4 << 3) + 6);
        a0 = fma(h0.x, (double)w4.x, a0); a1 = fma(h0.y, (double)w4.x, a1);
        a0 = fma(h1.x, (double)w4.y, a0); a1 = fma(h1.y, (double)w4.y, a1);
        a0 = fma(h2.x, (double)w4.z, a0); a1 = fma(h2.y, (double)w4.z, a1);
        a0 = fma(h3.x, (double)w4.w, a0); a1 = fma(h3.y, (double)w4.w, a1);
      }
      comb_l[t * 2 + 0] = a0; comb_l[t * 2 + 1] = a1;
    } else if (tb < 12) {              // out_mlp layer 3 + gia + stores
      const int g = tb / 6, c = tb - g * 6;
      double a = (double)ob3[c];
#pragma unroll 4
      for (int k = 0; k < 64; ++k) a = fma(o2_l[k * 2 + g], (double)ow3[k * 6 + c], a);
      const double gi_new = gia_l[g * 6 + c] + a;
      gia_l[g * 6 + c] = gi_new;
      const int s = s0 + g;
      dout[s * 300 + step * 6 + c] = (float)a;              // dws
      dout[76800 + s * 300 + step * 6 + c] = (float)gi_new; // ws
    }
    __syncthreads();
  }
}

extern "C" void kernel_launch(void* const* d_in, const int* in_sizes, int n_in,
                              void* d_out, int out_size, void* d_ws, size_t ws_size,
                              hipStream_t stream) {
  const float* data = (const float*)d_in[0];
  // d_in[1] = horizon (always 50)
  const float* ew1 = (const float*)d_in[2];
  const float* eb1 = (const float*)d_in[3];
  const float* ew2 = (const float*)d_in[4];
  const float* eb2 = (const float*)d_in[5];
  const float* ew3 = (const float*)d_in[6];
  const float* eb3 = (const float*)d_in[7];
  const float* mw1 = (const float*)d_in[8];
  const float* mb1 = (const float*)d_in[9];
  const float* mw2 = (const float*)d_in[10];
  const float* mb2 = (const float*)d_in[11];
  const float* mw3 = (const float*)d_in[12];
  const float* mb3 = (const float*)d_in[13];
  const float* wih = (const float*)d_in[14];
  const float* whh = (const float*)d_in[15];
  const float* bih = (const float*)d_in[16];
  const float* bhh = (const float*)d_in[17];
  const float* ow1 = (const float*)d_in[18];
  const float* ob1 = (const float*)d_in[19];
  const float* ow2 = (const float*)d_in[20];
  const float* ob2 = (const float*)d_in[21];
  const float* ow3 = (const float*)d_in[22];
  const float* ob3 = (const float*)d_in[23];
  float* out = (float*)d_out;

  char* ws = (char*)d_ws;
  float*    wh4  = (float*)(ws);                 // 786432 B
  unsigned* henc = (unsigned*)(ws + 786432);     // 524288 B
  double*   hg   = (double*)(ws + 1310720);      // 524288 B -> end 1835008

  prep_kernel<<<512, 256, 0, stream>>>(whh, wh4, henc);
  enc_kernel<<<512, 1024, 0, stream>>>(data, ew1, eb1, ew2, eb2, ew3, eb3, henc);
  gru_kernel<<<128, 1024, 0, stream>>>((const float*)henc,
                                       mw1, mb1, mw2, mb2, mw3, mb3,
                                       wih, wh4, bih, bhh,
                                       ow1, ob1, ow2, ob2, ow3, ob3,
                                       hg, out);
}

// Round 7
// 1740.830 us; speedup vs baseline: 1.4886x; 1.4886x over previous
//
#include <hip/hip_runtime.h>
#include <math.h>

// Problem constants
#define B_    256
#define NPTS  1024
#define T_    50

// ---------------------------------------------------------------------------
// ws layout (bytes):
//   [0,       786432)   wp   f32 [64][3][256][4]  packed W_hh:
//                       wp[((k4*3+j)*256+t)*4+c] = whh[(j*256+t)*256 + k4*4+c]
//   [786432,  1310720)  henc u32 [256][512]       (f32-bit maxpool via atomicMax)
// ---------------------------------------------------------------------------

__global__ __launch_bounds__(256) void prep_kernel(const float* __restrict__ whh,
                                                   float* __restrict__ wp,
                                                   unsigned* __restrict__ henc) {
  int idx = blockIdx.x * 256 + threadIdx.x;   // grid 768*256 = 196608
  if (idx < 196608) {
    int c = idx & 3;
    int r = idx >> 2;            // (k4*3+j)*256 + t
    int t2 = r & 255;
    int q = r >> 8;              // k4*3 + j
    int j = q % 3;
    int k4 = q / 3;
    wp[idx] = whh[(j * 256 + t2) * 256 + (k4 * 4 + c)];
  }
  if (idx < 131072) henc[idx] = 0u;           // bits 0 == +0.0f; relu>=0 valid
}

// ---------------------------------------------------------------------------
// Encoder (unchanged from passing round 6): block = half sample, grid 512.
// Wave-uniform output slices -> weights via scalar s_loads; LDS point tile.
// ---------------------------------------------------------------------------
__global__ __launch_bounds__(1024) void enc_kernel(
    const float* __restrict__ data,
    const float* __restrict__ w1, const float* __restrict__ b1,
    const float* __restrict__ w2, const float* __restrict__ b2,
    const float* __restrict__ w3, const float* __restrict__ b3,
    unsigned* __restrict__ henc) {
  __shared__ float h2t[128][66];
  const int t = threadIdx.x;
  const int b = blockIdx.x >> 1;
  const int half = blockIdx.x & 1;
  const int lane = t & 63;
  const int wv = __builtin_amdgcn_readfirstlane(t >> 6);   // wave id 0..15

  float m[32];
#pragma unroll
  for (int o = 0; o < 32; ++o) m[o] = 0.0f;                // relu via max w/ 0
  const float* __restrict__ w3b = w3 + wv * 32;

#pragma unroll 1
  for (int tile = 0; tile < 8; ++tile) {
    {
      const int ptg = b * NPTS + half * 512 + tile * 64 + lane;
      const float x0 = data[ptg * 3], x1 = data[ptg * 3 + 1], x2 = data[ptg * 3 + 2];
      float a[8];
#pragma unroll
      for (int c = 0; c < 8; ++c) a[c] = b2[wv * 8 + c];   // s_load
#pragma unroll 4
      for (int j = 0; j < 64; ++j) {                       // w1/b1 uniform
        float hj = fmaf(x0, w1[j], fmaf(x1, w1[64 + j], fmaf(x2, w1[128 + j], b1[j])));
        hj = fmaxf(hj, 0.0f);
        const float* __restrict__ w2r = w2 + j * 128 + wv * 8;  // s_load x8
#pragma unroll
        for (int c = 0; c < 8; ++c) a[c] = fmaf(hj, w2r[c], a[c]);
      }
#pragma unroll
      for (int c = 0; c < 8; ++c) h2t[wv * 8 + c][lane] = fmaxf(a[c], 0.0f);
    }
    __syncthreads();

    float acc[32];
#pragma unroll
    for (int o = 0; o < 32; ++o) acc[o] = b3[wv * 32 + o]; // s_load
#pragma unroll 4
    for (int k = 0; k < 128; ++k) {
      const float hk = h2t[k][lane];                       // ds_read_b32
      const float* __restrict__ wr = w3b + k * 512;        // uniform -> s_load
#pragma unroll
      for (int o = 0; o < 32; ++o) acc[o] = fmaf(hk, wr[o], acc[o]);
    }
#pragma unroll
    for (int o = 0; o < 32; ++o) m[o] = fmaxf(m[o], acc[o]);
    __syncthreads();                                       // h2t reuse guard
  }

#pragma unroll
  for (int off = 32; off > 0; off >>= 1) {
#pragma unroll
    for (int o = 0; o < 32; ++o) m[o] = fmaxf(m[o], __shfl_xor(m[o], off, 64));
  }
  if (lane == 0) {
    unsigned* __restrict__ hr = henc + b * 512 + wv * 32;
#pragma unroll
    for (int o = 0; o < 32; ++o) atomicMax(hr + o, __float_as_uint(m[o]));
  }
}

// ---------------------------------------------------------------------------
// GRU rollout, f64, grid 128, block = 2 samples x 1024 threads.
// Matvec on waves 0-3 (t<256): thread t owns channel t's r/z/n gate rows
// (3 outputs x 2 samples = 6 f64 acc regs). Per k4: 3 coalesced dwordx4
// w-loads (wp packing) + 4 broadcast ds_read_b128 of h + 24 f64 FMA ->
// per-wave 6144 FMA cyc/step = the 4-SIMD minimum. Gates fused into the
// same threads (comb never leaves registers; comb_l + its 415k bank
// conflicts deleted); h kept in hreg + published to h_l[g][k] (2-way).
// out_mlp (waves 4-5) overlaps the 3 matvec chunks; gia_l feedback written
// in chunk 3, consumed by gates after the loop-end barrier.
// All f64 dot chains ascending-k (round-3-validated formulas).
// ---------------------------------------------------------------------------
__global__ __launch_bounds__(1024) void gru_kernel(
    const float* __restrict__ henc,     // [256][512] (maxpool bits)
    const float* __restrict__ mw1, const float* __restrict__ mb1,
    const float* __restrict__ mw2, const float* __restrict__ mb2,
    const float* __restrict__ mw3, const float* __restrict__ mb3,
    const float* __restrict__ wih, const float* __restrict__ wp,
    const float* __restrict__ bih, const float* __restrict__ bhh,
    const float* __restrict__ ow1, const float* __restrict__ ob1,
    const float* __restrict__ ow2, const float* __restrict__ ob2,
    const float* __restrict__ ow3, const float* __restrict__ ob3,
    float* __restrict__ dout) {
  __shared__ __align__(16) double h_l[512];   // [g][i]
  __shared__ double g1_l[512];                // [g][o] (phase 0)
  __shared__ double g2_l[256];                // [g][o] (phase 0)
  __shared__ double o1_l[128];                // [g][j]
  __shared__ double o2_l[128];                // [g][j]
  __shared__ double gia_l[12];                // [g][c]
  __shared__ float wih_l[4608];
  __shared__ float bih_l[768];

  const int t = threadIdx.x;
  const int s0 = blockIdx.x << 1;

  for (int i = t; i < 4608; i += 1024) wih_l[i] = wih[i];
  if (t < 768) bih_l[t] = bih[t];

  // ---- phase 0: gru_h init MLP (512->256->128->256), f64 ----
  if (t < 512) {
    const int o = t & 255, g = t >> 8;                    // g wave-uniform
    const float* __restrict__ hrow = henc + ((s0 + g) << 9);   // uniform
    double a = (double)mb1[o];
#pragma unroll 4
    for (int k = 0; k < 512; ++k)
      a = fma((double)hrow[k], (double)mw1[k * 256 + o], a);
    g1_l[(g << 8) + o] = fmax(a, 0.0);
  }
  __syncthreads();
  if (t < 256) {
    const int o = t & 127, g = t >> 7;
    double a = (double)mb2[o];
#pragma unroll 4
    for (int k = 0; k < 256; ++k) a = fma(g1_l[(g << 8) + k], (double)mw2[k * 128 + o], a);
    g2_l[(g << 7) + o] = fmax(a, 0.0);
  }
  __syncthreads();
  if (t < 512) {
    const int o = t & 255, g = t >> 8;
    double a = (double)mb3[o];
#pragma unroll 4
    for (int k = 0; k < 128; ++k) a = fma(g2_l[(g << 7) + k], (double)mw3[k * 256 + o], a);
    h_l[(g << 8) + o] = a;
  }
  if (t < 12) gia_l[t] = 0.0;
  __syncthreads();

  // ---- matvec thread constants + prologue: comb_1 = bhh + Whh @ h0 ----
  double hreg0 = 0.0, hreg1 = 0.0, br = 0.0, bz = 0.0, bn = 0.0;
  double ar0 = 0.0, ar1 = 0.0, az0 = 0.0, az1 = 0.0, an0 = 0.0, an1 = 0.0;

#define MV_K4(k4) {                                                          \
    const int wbase = ((k4) * 3 * 256 + t) * 4;                              \
    const float4 wr = *(const float4*)(wp + wbase);                          \
    const float4 wz = *(const float4*)(wp + wbase + 1024);                   \
    const float4 wn = *(const float4*)(wp + wbase + 2048);                   \
    const double2 ha = *(const double2*)(h_l + ((k4) << 2));                 \
    const double2 hb = *(const double2*)(h_l + ((k4) << 2) + 2);             \
    const double2 hc = *(const double2*)(h_l + 256 + ((k4) << 2));           \
    const double2 hd = *(const double2*)(h_l + 256 + ((k4) << 2) + 2);       \
    ar0 = fma(ha.x, (double)wr.x, ar0); ar0 = fma(ha.y, (double)wr.y, ar0);  \
    ar0 = fma(hb.x, (double)wr.z, ar0); ar0 = fma(hb.y, (double)wr.w, ar0);  \
    az0 = fma(ha.x, (double)wz.x, az0); az0 = fma(ha.y, (double)wz.y, az0);  \
    az0 = fma(hb.x, (double)wz.z, az0); az0 = fma(hb.y, (double)wz.w, az0);  \
    an0 = fma(ha.x, (double)wn.x, an0); an0 = fma(ha.y, (double)wn.y, an0);  \
    an0 = fma(hb.x, (double)wn.z, an0); an0 = fma(hb.y, (double)wn.w, an0);  \
    ar1 = fma(hc.x, (double)wr.x, ar1); ar1 = fma(hc.y, (double)wr.y, ar1);  \
    ar1 = fma(hd.x, (double)wr.z, ar1); ar1 = fma(hd.y, (double)wr.w, ar1);  \
    az1 = fma(hc.x, (double)wz.x, az1); az1 = fma(hc.y, (double)wz.y, az1);  \
    az1 = fma(hd.x, (double)wz.z, az1); az1 = fma(hd.y, (double)wz.w, az1);  \
    an1 = fma(hc.x, (double)wn.x, an1); an1 = fma(hc.y, (double)wn.y, an1);  \
    an1 = fma(hd.x, (double)wn.z, an1); an1 = fma(hd.y, (double)wn.w, an1);  \
  }

  if (t < 256) {
    hreg0 = h_l[t]; hreg1 = h_l[256 + t];
    br = (double)bhh[t]; bz = (double)bhh[256 + t]; bn = (double)bhh[512 + t];
    ar0 = br; ar1 = br; az0 = bz; az1 = bz; an0 = bn; an1 = bn;
#pragma unroll 2
    for (int k4 = 0; k4 < 64; ++k4) MV_K4(k4);
  }
  __syncthreads();

  for (int step = 0; step < T_; ++step) {
    // ---- gates + h update (matvec threads; comb = acc regs) ----
    if (t < 256) {
      const int i = t;
      double gr0 = (double)bih_l[i], gz0 = (double)bih_l[256 + i],
             gn0 = (double)bih_l[512 + i];
      double gr1 = gr0, gz1 = gz0, gn1 = gn0;
#pragma unroll
      for (int a = 0; a < 6; ++a) {
        const double x0 = gia_l[a], x1 = gia_l[6 + a];
        const double vr = (double)wih_l[i * 6 + a];
        const double vz = (double)wih_l[(256 + i) * 6 + a];
        const double vn = (double)wih_l[(512 + i) * 6 + a];
        gr0 = fma(vr, x0, gr0); gr1 = fma(vr, x1, gr1);
        gz0 = fma(vz, x0, gz0); gz1 = fma(vz, x1, gz1);
        gn0 = fma(vn, x0, gn0); gn1 = fma(vn, x1, gn1);
      }
      const double rv0 = 1.0 / (1.0 + exp(-(ar0 + gr0)));
      const double zv0 = 1.0 / (1.0 + exp(-(az0 + gz0)));
      const double nv0 = tanh(fma(rv0, an0, gn0));
      hreg0 = fma(zv0, hreg0 - nv0, nv0);
      h_l[i] = hreg0;
      const double rv1 = 1.0 / (1.0 + exp(-(ar1 + gr1)));
      const double zv1 = 1.0 / (1.0 + exp(-(az1 + gz1)));
      const double nv1 = tanh(fma(rv1, an1, gn1));
      hreg1 = fma(zv1, hreg1 - nv1, nv1);
      h_l[256 + i] = hreg1;
      ar0 = br; ar1 = br; az0 = bz; az1 = bz; an0 = bn; an1 = bn;
    }
    __syncthreads();                    // h_s published

    // ---- chunk 1: matvec k4 0..20 || out_mlp L1 ----
    if (t < 256) {
#pragma unroll 2
      for (int k4 = 0; k4 < 21; ++k4) MV_K4(k4);
    } else if (t < 384) {
      const int j = (t - 256) & 63, g = (t - 256) >> 6;
      double a = (double)ob1[j];
#pragma unroll 4
      for (int k = 0; k < 256; ++k)
        a = fma(h_l[(g << 8) + k], (double)ow1[k * 64 + j], a);  // h broadcast
      o1_l[(g << 6) + j] = fmax(a, 0.0);
    }
    __syncthreads();

    // ---- chunk 2: matvec k4 21..41 || out_mlp L2 ----
    if (t < 256) {
#pragma unroll 2
      for (int k4 = 21; k4 < 42; ++k4) MV_K4(k4);
    } else if (t < 384) {
      const int j = (t - 256) & 63, g = (t - 256) >> 6;
      double a = (double)ob2[j];
#pragma unroll 4
      for (int k = 0; k < 64; ++k)
        a = fma(o1_l[(g << 6) + k], (double)ow2[k * 64 + j], a);
      o2_l[(g << 6) + j] = fmax(a, 0.0);
    }
    __syncthreads();

    // ---- chunk 3: matvec k4 42..63 || out_mlp L3 + gia + stores ----
    if (t < 256) {
#pragma unroll 2
      for (int k4 = 42; k4 < 64; ++k4) MV_K4(k4);
    } else if (t < 268) {
      const int tb = t - 256;
      const int g = tb / 6, c = tb - g * 6;
      double a = (double)ob3[c];
#pragma unroll 4
      for (int k = 0; k < 64; ++k)
        a = fma(o2_l[(g << 6) + k], (double)ow3[k * 6 + c], a);
      const double gi_new = gia_l[g * 6 + c] + a;
      gia_l[g * 6 + c] = gi_new;
      const int s = s0 + g;
      dout[s * 300 + step * 6 + c] = (float)a;              // dws
      dout[76800 + s * 300 + step * 6 + c] = (float)gi_new; // ws
    }
    __syncthreads();                    // gia + comb ready for next gates
  }
#undef MV_K4
}

extern "C" void kernel_launch(void* const* d_in, const int* in_sizes, int n_in,
                              void* d_out, int out_size, void* d_ws, size_t ws_size,
                              hipStream_t stream) {
  const float* data = (const float*)d_in[0];
  // d_in[1] = horizon (always 50)
  const float* ew1 = (const float*)d_in[2];
  const float* eb1 = (const float*)d_in[3];
  const float* ew2 = (const float*)d_in[4];
  const float* eb2 = (const float*)d_in[5];
  const float* ew3 = (const float*)d_in[6];
  const float* eb3 = (const float*)d_in[7];
  const float* mw1 = (const float*)d_in[8];
  const float* mb1 = (const float*)d_in[9];
  const float* mw2 = (const float*)d_in[10];
  const float* mb2 = (const float*)d_in[11];
  const float* mw3 = (const float*)d_in[12];
  const float* mb3 = (const float*)d_in[13];
  const float* wih = (const float*)d_in[14];
  const float* whh = (const float*)d_in[15];
  const float* bih = (const float*)d_in[16];
  const float* bhh = (const float*)d_in[17];
  const float* ow1 = (const float*)d_in[18];
  const float* ob1 = (const float*)d_in[19];
  const float* ow2 = (const float*)d_in[20];
  const float* ob2 = (const float*)d_in[21];
  const float* ow3 = (const float*)d_in[22];
  const float* ob3 = (const float*)d_in[23];
  float* out = (float*)d_out;

  char* ws = (char*)d_ws;
  float*    wp   = (float*)(ws);                 // 786432 B
  unsigned* henc = (unsigned*)(ws + 786432);     // 524288 B -> end 1310720

  prep_kernel<<<768, 256, 0, stream>>>(whh, wp, henc);
  enc_kernel<<<512, 1024, 0, stream>>>(data, ew1, eb1, ew2, eb2, ew3, eb3, henc);
  gru_kernel<<<128, 1024, 0, stream>>>((const float*)henc,
                                       mw1, mb1, mw2, mb2, mw3, mb3,
                                       wih, wp, bih, bhh,
                                       ow1, ob1, ow2, ob2, ow3, ob3,
                                       out);
}

// Round 8
// 1338.118 us; speedup vs baseline: 1.9366x; 1.3010x over previous
//
#include <hip/hip_runtime.h>
#include <math.h>

// Problem constants
#define B_    256
#define NPTS  1024
#define T_    50

// ---------------------------------------------------------------------------
// ws layout (bytes):
//   [0,       786432)   wp   f32 [64][3][256][4]  packed W_hh (round-7 layout)
//   [786432,  1310720)  henc u32 [256][512]       (f32-bit maxpool via atomicMax)
//   [1310720, 1441792)  ow1d f64 [256][64]
//   [1441792, 1474560)  ow2d f64 [64][64]
//   [1474560, 1477632)  ow3d f64 [64][6]
// ---------------------------------------------------------------------------

__global__ __launch_bounds__(256) void prep_kernel(
    const float* __restrict__ whh, const float* __restrict__ ow1,
    const float* __restrict__ ow2, const float* __restrict__ ow3,
    float* __restrict__ wp, unsigned* __restrict__ henc,
    double* __restrict__ ow1d, double* __restrict__ ow2d,
    double* __restrict__ ow3d) {
  int idx = blockIdx.x * 256 + threadIdx.x;   // grid 768*256 = 196608
  if (idx < 196608) {
    int c = idx & 3;
    int r = idx >> 2;            // (k4*3+j)*256 + t
    int t2 = r & 255;
    int q = r >> 8;              // k4*3 + j
    int j = q % 3;
    int k4 = q / 3;
    wp[idx] = whh[(j * 256 + t2) * 256 + (k4 * 4 + c)];
  }
  if (idx < 131072) henc[idx] = 0u;           // bits 0 == +0.0f; relu>=0 valid
  if (idx < 16384) ow1d[idx] = (double)ow1[idx];
  if (idx < 4096)  ow2d[idx] = (double)ow2[idx];
  if (idx < 384)   ow3d[idx] = (double)ow3[idx];
}

// ---------------------------------------------------------------------------
// Encoder (byte-identical math to passing rounds 5-7): block = half sample,
// grid 512. Wave-uniform output slices -> weights via scalar s_loads.
// ---------------------------------------------------------------------------
__global__ __launch_bounds__(1024) void enc_kernel(
    const float* __restrict__ data,
    const float* __restrict__ w1, const float* __restrict__ b1,
    const float* __restrict__ w2, const float* __restrict__ b2,
    const float* __restrict__ w3, const float* __restrict__ b3,
    unsigned* __restrict__ henc) {
  __shared__ float h2t[128][66];
  const int t = threadIdx.x;
  const int b = blockIdx.x >> 1;
  const int half = blockIdx.x & 1;
  const int lane = t & 63;
  const int wv = __builtin_amdgcn_readfirstlane(t >> 6);   // wave id 0..15

  float m[32];
#pragma unroll
  for (int o = 0; o < 32; ++o) m[o] = 0.0f;                // relu via max w/ 0
  const float* __restrict__ w3b = w3 + wv * 32;

#pragma unroll 1
  for (int tile = 0; tile < 8; ++tile) {
    {
      const int ptg = b * NPTS + half * 512 + tile * 64 + lane;
      const float x0 = data[ptg * 3], x1 = data[ptg * 3 + 1], x2 = data[ptg * 3 + 2];
      float a[8];
#pragma unroll
      for (int c = 0; c < 8; ++c) a[c] = b2[wv * 8 + c];   // s_load
#pragma unroll 4
      for (int j = 0; j < 64; ++j) {                       // w1/b1 uniform
        float hj = fmaf(x0, w1[j], fmaf(x1, w1[64 + j], fmaf(x2, w1[128 + j], b1[j])));
        hj = fmaxf(hj, 0.0f);
        const float* __restrict__ w2r = w2 + j * 128 + wv * 8;  // s_load x8
#pragma unroll
        for (int c = 0; c < 8; ++c) a[c] = fmaf(hj, w2r[c], a[c]);
      }
#pragma unroll
      for (int c = 0; c < 8; ++c) h2t[wv * 8 + c][lane] = fmaxf(a[c], 0.0f);
    }
    __syncthreads();

    float acc[32];
#pragma unroll
    for (int o = 0; o < 32; ++o) acc[o] = b3[wv * 32 + o]; // s_load
#pragma unroll 4
    for (int k = 0; k < 128; ++k) {
      const float hk = h2t[k][lane];                       // ds_read_b32
      const float* __restrict__ wr = w3b + k * 512;        // uniform -> s_load
#pragma unroll
      for (int o = 0; o < 32; ++o) acc[o] = fmaf(hk, wr[o], acc[o]);
    }
#pragma unroll
    for (int o = 0; o < 32; ++o) m[o] = fmaxf(m[o], acc[o]);
    __syncthreads();                                       // h2t reuse guard
  }

#pragma unroll
  for (int off = 32; off > 0; off >>= 1) {
#pragma unroll
    for (int o = 0; o < 32; ++o) m[o] = fmaxf(m[o], __shfl_xor(m[o], off, 64));
  }
  if (lane == 0) {
    unsigned* __restrict__ hr = henc + b * 512 + wv * 32;
#pragma unroll
    for (int o = 0; o < 32; ++o) atomicMax(hr + o, __float_as_uint(m[o]));
  }
}

// ---------------------------------------------------------------------------
// Fast f64 exp (Cody-Waite + degree-13 Taylor, exact 1/k! coeffs, branch-
// free, ~1 ulp for |x| < 700). Perturbs vs libm at ~1e-16 rel -> invisible
// at f32 output rounding (f64-perturbation invariance proven rounds 4-7).
// ---------------------------------------------------------------------------
__device__ __forceinline__ double fexp(double x) {
  const double n = rint(x * 1.44269504088896338700e+00);
  const double r = fma(-n, 1.90821492927058770002e-10,
                       fma(-n, 6.93147180369123816490e-01, x));
  double p = 1.0 / 6227020800.0;                 // 1/13!
  p = fma(p, r, 1.0 / 479001600.0);
  p = fma(p, r, 1.0 / 39916800.0);
  p = fma(p, r, 1.0 / 3628800.0);
  p = fma(p, r, 1.0 / 362880.0);
  p = fma(p, r, 1.0 / 40320.0);
  p = fma(p, r, 1.0 / 5040.0);
  p = fma(p, r, 1.0 / 720.0);
  p = fma(p, r, 1.0 / 120.0);
  p = fma(p, r, 1.0 / 24.0);
  p = fma(p, r, 1.0 / 6.0);
  p = fma(p, r, 0.5);
  p = fma(p, r, 1.0);
  p = fma(p, r, 1.0);
  return ldexp(p, (int)n);
}
__device__ __forceinline__ double fsigm(double x) { return 1.0 / (1.0 + fexp(-x)); }
__device__ __forceinline__ double ftanh(double y) {
  const double e = fexp(-2.0 * y);
  return (1.0 - e) / (1.0 + e);
}

// ---------------------------------------------------------------------------
// GRU rollout, f64, grid 128, block = 2 samples x 640 threads (10 waves).
// t<512: matvec, thread = (channel c = t&255, k-half hh = t>>8); each owns
// channel c's r/z/n rows over 32 k4 -> 2 waves/SIMD hide each other's
// latency (round 7: 1 wave/SIMD, VALUBusy 14.6%). Partner-half partials
// exchanged via LDS pp[]; gates split by sample g = hh (halves the
// transcendental chain per thread) using fexp/fsigm/ftanh (libm f64
// exp/tanh with divisions was ~10k cyc/step). t in [512,640): out_mlp on
// pre-converted f64 weights, overlapped with matvec chunks (c1: L1 k-split;
// c2: combine+L2 (wave-synchronous); c3: L3+gia+stores).
// All f64 dot chains ascending-k; half-split reassociation is f64-invisible.
// ---------------------------------------------------------------------------
__global__ __launch_bounds__(640) void gru_kernel(
    const float* __restrict__ henc,     // [256][512] (maxpool bits)
    const float* __restrict__ mw1, const float* __restrict__ mb1,
    const float* __restrict__ mw2, const float* __restrict__ mb2,
    const float* __restrict__ mw3, const float* __restrict__ mb3,
    const float* __restrict__ wih, const float* __restrict__ wp,
    const float* __restrict__ bih, const float* __restrict__ bhh,
    const double* __restrict__ ow1d, const float* __restrict__ ob1,
    const double* __restrict__ ow2d, const float* __restrict__ ob2,
    const double* __restrict__ ow3d, const float* __restrict__ ob3,
    float* __restrict__ dout) {
  __shared__ __align__(16) double h_l[512];   // [g][c]
  __shared__ double pp[2][3][256];  // [publisher-half][gate][c] partner partials
  __shared__ double g1_l[512];                // phase 0
  __shared__ double g2_l[256];                // phase 0
  __shared__ double o1p[2][2][64];            // [q][g][j] L1 partials
  __shared__ double o1_l[2][64];
  __shared__ double o2_l[2][64];
  __shared__ double gia_l[12];                // [g][c]
  __shared__ double wihd[4608];
  __shared__ double bihd[768];

  const int t = threadIdx.x;
  const int s0 = blockIdx.x << 1;

  for (int i = t; i < 4608; i += 640) wihd[i] = (double)wih[i];
  for (int i = t; i < 768; i += 640) bihd[i] = (double)bih[i];

  // ---- phase 0: gru_h init MLP (512->256->128->256), f64 (round-7 math) --
  if (t < 512) {
    const int o = t & 255, g = t >> 8;                    // g wave-uniform
    const float* __restrict__ hrow = henc + ((s0 + g) << 9);   // uniform
    double a = (double)mb1[o];
#pragma unroll 4
    for (int k = 0; k < 512; ++k)
      a = fma((double)hrow[k], (double)mw1[k * 256 + o], a);
    g1_l[(g << 8) + o] = fmax(a, 0.0);
  }
  __syncthreads();
  if (t < 256) {
    const int o = t & 127, g = t >> 7;
    double a = (double)mb2[o];
#pragma unroll 4
    for (int k = 0; k < 256; ++k) a = fma(g1_l[(g << 8) + k], (double)mw2[k * 128 + o], a);
    g2_l[(g << 7) + o] = fmax(a, 0.0);
  }
  __syncthreads();
  if (t < 512) {
    const int o = t & 255, g = t >> 8;
    double a = (double)mb3[o];
#pragma unroll 4
    for (int k = 0; k < 128; ++k) a = fma(g2_l[(g << 7) + k], (double)mw3[k * 256 + o], a);
    h_l[(g << 8) + o] = a;
  }
  if (t < 12) gia_l[t] = 0.0;
  __syncthreads();

  // ---- matvec/gate thread constants ----
  const int c = t & 255;
  const int hh = (t >> 8) & 1;                 // k-half AND owned sample g
  const int khome = hh << 5;                   // k4 range [khome, khome+32)
  const double br = (t < 512 && hh == 0) ? (double)bhh[c] : 0.0;
  const double bz = (t < 512 && hh == 0) ? (double)bhh[256 + c] : 0.0;
  const double bn = (t < 512 && hh == 0) ? (double)bhh[512 + c] : 0.0;
  double hreg = (t < 512) ? h_l[(hh << 8) + c] : 0.0;
  const int tb = t - 512;

  double ar0, ar1, az0, az1, an0, an1;

#define MV_K4(k4) {                                                          \
    const int wbase = ((k4) * 768 + c) * 4;                                  \
    const float4 wr = *(const float4*)(wp + wbase);                          \
    const float4 wz = *(const float4*)(wp + wbase + 1024);                   \
    const float4 wn = *(const float4*)(wp + wbase + 2048);                   \
    const double2 ha = *(const double2*)(h_l + ((k4) << 2));                 \
    const double2 hb = *(const double2*)(h_l + ((k4) << 2) + 2);             \
    const double2 hc = *(const double2*)(h_l + 256 + ((k4) << 2));           \
    const double2 hd = *(const double2*)(h_l + 256 + ((k4) << 2) + 2);       \
    ar0 = fma(ha.x, (double)wr.x, ar0); ar0 = fma(ha.y, (double)wr.y, ar0);  \
    ar0 = fma(hb.x, (double)wr.z, ar0); ar0 = fma(hb.y, (double)wr.w, ar0);  \
    az0 = fma(ha.x, (double)wz.x, az0); az0 = fma(ha.y, (double)wz.y, az0);  \
    az0 = fma(hb.x, (double)wz.z, az0); az0 = fma(hb.y, (double)wz.w, az0);  \
    an0 = fma(ha.x, (double)wn.x, an0); an0 = fma(ha.y, (double)wn.y, an0);  \
    an0 = fma(hb.x, (double)wn.z, an0); an0 = fma(hb.y, (double)wn.w, an0);  \
    ar1 = fma(hc.x, (double)wr.x, ar1); ar1 = fma(hc.y, (double)wr.y, ar1);  \
    ar1 = fma(hd.x, (double)wr.z, ar1); ar1 = fma(hd.y, (double)wr.w, ar1);  \
    az1 = fma(hc.x, (double)wz.x, az1); az1 = fma(hc.y, (double)wz.y, az1);  \
    az1 = fma(hd.x, (double)wz.z, az1); az1 = fma(hd.y, (double)wz.w, az1);  \
    an1 = fma(hc.x, (double)wn.x, an1); an1 = fma(hc.y, (double)wn.y, an1);  \
    an1 = fma(hd.x, (double)wn.z, an1); an1 = fma(hd.y, (double)wn.w, an1);  \
  }
#define MV_PUBLISH() {                                                       \
    pp[hh][0][c] = hh ? ar0 : ar1;                                           \
    pp[hh][1][c] = hh ? az0 : az1;                                           \
    pp[hh][2][c] = hh ? an0 : an1;                                           \
  }

  // ---- prologue: both halves' partials of comb(h0) ----
  if (t < 512) {
    ar0 = br; ar1 = br; az0 = bz; az1 = bz; an0 = bn; an1 = bn;
#pragma unroll 2
    for (int k4 = khome; k4 < khome + 32; ++k4) MV_K4(k4);
    MV_PUBLISH();
  }
  __syncthreads();

  for (int step = 0; step < T_; ++step) {
    // ---- gates for sample g=hh (t<512): comb = own-half + partner-half ----
    if (t < 512) {
      const double cr = (hh ? ar1 : ar0) + pp[hh ^ 1][0][c];
      const double cz = (hh ? az1 : az0) + pp[hh ^ 1][1][c];
      const double cn = (hh ? an1 : an0) + pp[hh ^ 1][2][c];
      double gr = bihd[c], gz = bihd[256 + c], gn = bihd[512 + c];
#pragma unroll
      for (int a = 0; a < 6; ++a) {
        const double xa = gia_l[hh * 6 + a];
        gr = fma(wihd[c * 6 + a], xa, gr);
        gz = fma(wihd[(256 + c) * 6 + a], xa, gz);
        gn = fma(wihd[(512 + c) * 6 + a], xa, gn);
      }
      const double rv = fsigm(cr + gr);
      const double zv = fsigm(cz + gz);
      const double nv = ftanh(fma(rv, cn, gn));
      hreg = fma(zv, hreg - nv, nv);
      h_l[(hh << 8) + c] = hreg;
      ar0 = br; ar1 = br; az0 = bz; az1 = bz; an0 = bn; an1 = bn;
    }
    __syncthreads();                    // h published

    // ---- c1: matvec k4 [khome, khome+11) || out_mlp L1 (k-split) ----
    if (t < 512) {
#pragma unroll 2
      for (int k4 = khome; k4 < khome + 11; ++k4) MV_K4(k4);
    } else if (tb < 128) {
      const int j = tb & 63, q = tb >> 6;
      double a0 = (q == 0) ? (double)ob1[j] : 0.0;
      double a1 = a0;
      const int k0 = q << 7;
#pragma unroll 4
      for (int k = k0; k < k0 + 128; ++k) {
        const double wv = ow1d[k * 64 + j];               // coalesced x2
        a0 = fma(h_l[k], wv, a0);                         // h broadcast
        a1 = fma(h_l[256 + k], wv, a1);
      }
      o1p[q][0][j] = a0; o1p[q][1][j] = a1;
    }
    __syncthreads();

    // ---- c2: matvec k4 [khome+11, khome+22) || combine o1 + L2 ----
    if (t < 512) {
#pragma unroll 2
      for (int k4 = khome + 11; k4 < khome + 22; ++k4) MV_K4(k4);
    } else if (tb < 64) {
      const int j = tb;
      o1_l[0][j] = fmax(o1p[0][0][j] + o1p[1][0][j], 0.0);
      o1_l[1][j] = fmax(o1p[0][1][j] + o1p[1][1][j], 0.0);
      __builtin_amdgcn_wave_barrier();                    // wave-sync LDS
      double b0 = (double)ob2[j], b1 = b0;
#pragma unroll 4
      for (int k = 0; k < 64; ++k) {
        const double wv = ow2d[k * 64 + j];
        b0 = fma(o1_l[0][k], wv, b0);
        b1 = fma(o1_l[1][k], wv, b1);
      }
      o2_l[0][j] = fmax(b0, 0.0);
      o2_l[1][j] = fmax(b1, 0.0);
    }
    __syncthreads();

    // ---- c3: matvec k4 [khome+22, khome+32) + publish || L3+gia+stores ----
    if (t < 512) {
#pragma unroll 2
      for (int k4 = khome + 22; k4 < khome + 32; ++k4) MV_K4(k4);
      MV_PUBLISH();
    } else if (tb < 12) {
      const int g = tb / 6, cc = tb - g * 6;
      double a = (double)ob3[cc];
#pragma unroll 4
      for (int k = 0; k < 64; ++k) a = fma(o2_l[g][k], ow3d[k * 6 + cc], a);
      const double gi_new = gia_l[g * 6 + cc] + a;
      gia_l[g * 6 + cc] = gi_new;
      const int s = s0 + g;
      dout[s * 300 + step * 6 + cc] = (float)a;              // dws
      dout[76800 + s * 300 + step * 6 + cc] = (float)gi_new; // ws
    }
    __syncthreads();                    // pp + gia ready for next gates
  }
#undef MV_K4
#undef MV_PUBLISH
}

extern "C" void kernel_launch(void* const* d_in, const int* in_sizes, int n_in,
                              void* d_out, int out_size, void* d_ws, size_t ws_size,
                              hipStream_t stream) {
  const float* data = (const float*)d_in[0];
  // d_in[1] = horizon (always 50)
  const float* ew1 = (const float*)d_in[2];
  const float* eb1 = (const float*)d_in[3];
  const float* ew2 = (const float*)d_in[4];
  const float* eb2 = (const float*)d_in[5];
  const float* ew3 = (const float*)d_in[6];
  const float* eb3 = (const float*)d_in[7];
  const float* mw1 = (const float*)d_in[8];
  const float* mb1 = (const float*)d_in[9];
  const float* mw2 = (const float*)d_in[10];
  const float* mb2 = (const float*)d_in[11];
  const float* mw3 = (const float*)d_in[12];
  const float* mb3 = (const float*)d_in[13];
  const float* wih = (const float*)d_in[14];
  const float* whh = (const float*)d_in[15];
  const float* bih = (const float*)d_in[16];
  const float* bhh = (const float*)d_in[17];
  const float* ow1 = (const float*)d_in[18];
  const float* ob1 = (const float*)d_in[19];
  const float* ow2 = (const float*)d_in[20];
  const float* ob2 = (const float*)d_in[21];
  const float* ow3 = (const float*)d_in[22];
  const float* ob3 = (const float*)d_in[23];
  float* out = (float*)d_out;

  char* ws = (char*)d_ws;
  float*    wp   = (float*)(ws);                 // 786432 B
  unsigned* henc = (unsigned*)(ws + 786432);     // 524288 B
  double*   ow1d = (double*)(ws + 1310720);      // 131072 B
  double*   ow2d = (double*)(ws + 1441792);      // 32768 B
  double*   ow3d = (double*)(ws + 1474560);      // 3072 B -> end 1477632

  prep_kernel<<<768, 256, 0, stream>>>(whh, ow1, ow2, ow3, wp, henc,
                                       ow1d, ow2d, ow3d);
  enc_kernel<<<512, 1024, 0, stream>>>(data, ew1, eb1, ew2, eb2, ew3, eb3, henc);
  gru_kernel<<<128, 640, 0, stream>>>((const float*)henc,
                                      mw1, mb1, mw2, mb2, mw3, mb3,
                                      wih, wp, bih, bhh,
                                      ow1d, ob1, ow2d, ob2, ow3d, ob3,
                                      out);
}